// Round 14
// baseline (197.620 us; speedup 1.0000x reference)
//
#include <hip/hip_runtime.h>

typedef __attribute__((ext_vector_type(8))) short bf16x8;
typedef __attribute__((ext_vector_type(4))) float f32x4;
typedef __attribute__((ext_vector_type(4))) _Float16 f16x4;
typedef __attribute__((ext_vector_type(2))) unsigned int u32x2;

#define B_N 8
#define S_N 2048
#define D_N 128
#define W_N 16
#define G_N 512
#define CH 32      /* chains per block */
#define ROWS 47    /* xg rows 0..46 used; 63 KB total LDS */

#define L1 1.4426950408889634f   /* log2(e)   */
#define L2 2.8853900817779268f   /* 2*log2(e) */

// round-to-nearest-even fp32 -> bf16
__device__ __forceinline__ short f2bf(float f) {
  union { float f; unsigned u; } v; v.f = f;
  unsigned r = v.u + 0x7fffu + ((v.u >> 16) & 1u);
  return (short)(r >> 16);
}

__device__ __forceinline__ bf16x8 cvt8(const float* p) {
  f32x4 a = *(const f32x4*)p;
  f32x4 b = *(const f32x4*)(p + 4);
  bf16x8 v;
  v[0] = f2bf(a[0]); v[1] = f2bf(a[1]); v[2] = f2bf(a[2]); v[3] = f2bf(a[3]);
  v[4] = f2bf(b[0]); v[5] = f2bf(b[1]); v[6] = f2bf(b[2]); v[7] = f2bf(b[3]);
  return v;
}

// ---------------------------------------------------------------------------
// Fused LocalRNN, 32 chains/block, 512 blocks, 512 threads (8 waves).
//
// OCCUPANCY DIAGNOSIS (R13): occupancy pinned at 21% (1 WG/CU) across LDS
// 63-112 KB and arch-VGPR 108-120. Explanation: gfx950's UNIFIED VGPR+AGPR
// file — the counter reports only arch VGPRs; unified total at (512,2) is
// ~136-184/wave > 128 -> 2 waves/SIMD -> 1 WG/CU, LDS irrelevant. (R3's
// (512,4) "64 VGPR" was 64 arch + 64 AGPR = the 128 cap, met by spilling.)
//
// THIS ROUND'S SINGLE VARIABLE: __launch_bounds__ (512,2) -> (512,4).
// Cap = 128 unified regs/wave. Lean live set (~120-136: wf 64 + acc 16 +
// hf 8 (K-split) + c 8 + addr/temps) should fit with only benign phase-1
// spills (bias), unlike R3's fat kernel (wf -> scratch in-loop).
// SPILL SENTINEL: WRITE_SIZE must stay ~8.2 MB; if >>20 MB the cap lost,
// revert to (512,2) and pivot to CH=64 + cg-interleave.
//
// Wave wv owns gate tiles {wv, wv+8, wv+16, wv+24} (i,f,g,o for one (chain,d)
// lane-local); per step 2 chain-groups sequentially; w_hh in VGPRs (time-
// shared with w_ih); h round-trips bf16 through double-buffered swizzled LDS;
// 1 barrier/step. LSTM: common-denominator form, 7 trans/element:
//   cn = [c(1+ei)(1+eg) + (1-eg)(1+ef)] / [(1+ef)(1+ei)(1+eg)]
//   h  = (1-ec) / [(1+eo)(1+ec)]
// ---------------------------------------------------------------------------
__global__ void __launch_bounds__(512, 4)
fused_rnn(const float* __restrict__ x, const float* __restrict__ w_ih,
          const float* __restrict__ w_hh, const float* __restrict__ b_ih,
          const float* __restrict__ b_hh, float* __restrict__ out) {
  __shared__ char xg_s[ROWS * 1024];        // 47 KB: f16 [row][gate], swizzled
  __shared__ char hbuf[2][CH * 256];        // 2x8 KB: bf16 [chain][k], swizzled
                                            // total 63 KB

  const int tid  = threadIdx.x;
  const int lane = tid & 63;
  const int wv   = tid >> 6;                // 0..7, gate-slice
  const int lm   = lane & 15;
  const int q    = lane >> 4;
  const int n0   = blockIdx.x * CH;
  const int b    = n0 >> 11;                // 2048 chains per batch, CH | 2048
  const int s0   = n0 & (S_N - 1);

  // ---------------- phase 1: input projection into LDS (f16) ----------------
  bf16x8 wf[4][4];   // A fragments: weight[g = tg*16+lm][k = kt*32 + q*8 + j]
#pragma unroll
  for (int i = 0; i < 4; ++i) {
    const int g = (wv + 8 * i) * 16 + lm;
#pragma unroll
    for (int kt = 0; kt < 4; ++kt)
      wf[i][kt] = cvt8(w_ih + g * D_N + kt * 32 + q * 8);
  }

  {
    f32x4 bias[4];
#pragma unroll
    for (int i = 0; i < 4; ++i) {
      const int g0 = (wv + 8 * i) * 16 + 4 * q;
      f32x4 bi = *(const f32x4*)(b_ih + g0);
      f32x4 bh = *(const f32x4*)(b_hh + g0);
      bias[i].x = bi.x + bh.x; bias[i].y = bi.y + bh.y;
      bias[i].z = bi.z + bh.z; bias[i].w = bi.w + bh.w;
    }

#pragma unroll
    for (int rg = 0; rg < 3; ++rg) {
      const int r = rg * 16 + lm;            // 0..47; row 47 not stored
      const int t = s0 - (W_N - 1) + r;      // x timestep
      int tc = t < 0 ? 0 : t;
      tc = tc < S_N - 1 ? tc : S_N - 1;      // clamp (r=47 on last block)
      const bool valid = (t >= 0);
      const float* xr = x + ((long)b * S_N + tc) * D_N;
      bf16x8 xf[4];
#pragma unroll
      for (int kt = 0; kt < 4; ++kt) {
        if (valid) xf[kt] = cvt8(xr + kt * 32 + q * 8);
        else { bf16x8 z; for (int e = 0; e < 8; ++e) z[e] = 0; xf[kt] = z; }
      }
      f32x4 acc[4] = {{0,0,0,0},{0,0,0,0},{0,0,0,0},{0,0,0,0}};
#pragma unroll
      for (int i = 0; i < 4; ++i)
#pragma unroll
        for (int kt = 0; kt < 4; ++kt)
          acc[i] = __builtin_amdgcn_mfma_f32_16x16x32_bf16(wf[i][kt], xf[kt], acc[i], 0, 0, 0);
      if (r < ROWS) {                        // row 47 would be OOB
#pragma unroll
        for (int i = 0; i < 4; ++i) {
          const int g0 = (wv + 8 * i) * 16 + 4 * q;
          const int byte = (r * 1024 + g0 * 2) ^ ((r & 7) << 4);
          f16x4 hv;
          hv[0] = (_Float16)(acc[i][0] + bias[i].x);
          hv[1] = (_Float16)(acc[i][1] + bias[i].y);
          hv[2] = (_Float16)(acc[i][2] + bias[i].z);
          hv[3] = (_Float16)(acc[i][3] + bias[i].w);
          *(f16x4*)(xg_s + byte) = hv;
        }
      }
    }
  }

  // reload fragment array with w_hh (time-shared registers)
#pragma unroll
  for (int i = 0; i < 4; ++i) {
    const int g = (wv + 8 * i) * 16 + lm;
#pragma unroll
    for (int kt = 0; kt < 4; ++kt)
      wf[i][kt] = cvt8(w_hh + g * D_N + kt * 32 + q * 8);
  }
  __syncthreads();

  // ---------------- phase 2: 16-step recurrence, 2 chain-groups ----------------
  const int swz = (lm & 7) << 4;
  const int wrb = (lm * 256 + (16 * wv + 4 * q) * 2) ^ swz;     // 8B h store
  int rdb[4];
#pragma unroll
  for (int kt = 0; kt < 4; ++kt)
    rdb[kt] = (lm * 256 + kt * 64 + q * 16) ^ swz;              // 16B h loads

  f32x4 c[2] = {{0,0,0,0},{0,0,0,0}};

#pragma unroll
  for (int w = 0; w < W_N; ++w) {
#pragma unroll
    for (int cg = 0; cg < 2; ++cg) {
      // gate init from f16 xg (biases folded in)
      const int row = cg * 16 + lm + w;      // 0..46
      f32x4 acc[4];
#pragma unroll
      for (int i = 0; i < 4; ++i) {
        const int g0 = (wv + 8 * i) * 16 + 4 * q;
        const int byte = (row * 1024 + g0 * 2) ^ ((row & 7) << 4);
        f16x4 xv = *(const f16x4*)(xg_s + byte);
        acc[i][0] = (float)xv[0]; acc[i][1] = (float)xv[1];
        acc[i][2] = (float)xv[2]; acc[i][3] = (float)xv[3];
      }

      if (w > 0) {
        const char* bb = hbuf[(w - 1) & 1] + cg * 4096;
        // K-split: only 2 hf fragments (8 regs) live at a time
#pragma unroll
        for (int kh = 0; kh < 2; ++kh) {
          bf16x8 hf0 = *(const bf16x8*)(bb + rdb[2 * kh]);
          bf16x8 hf1 = *(const bf16x8*)(bb + rdb[2 * kh + 1]);
#pragma unroll
          for (int i = 0; i < 4; ++i) {
            acc[i] = __builtin_amdgcn_mfma_f32_16x16x32_bf16(wf[i][2 * kh],     hf0, acc[i], 0, 0, 0);
            acc[i] = __builtin_amdgcn_mfma_f32_16x16x32_bf16(wf[i][2 * kh + 1], hf1, acc[i], 0, 0, 0);
          }
        }
      }

      // acc[0]=i, acc[1]=f, acc[2]=g~, acc[3]=o for d=16wv+4q+r, chain=cg*16+lm
      // combined-denominator LSTM: 5 exp2 + 2 rcp per element
      float hr[4];
#pragma unroll
      for (int r = 0; r < 4; ++r) {
        float ei = __builtin_amdgcn_exp2f(-L1 * acc[0][r]);
        float ef = __builtin_amdgcn_exp2f(-L1 * acc[1][r]);
        float eg = __builtin_amdgcn_exp2f(-L2 * acc[2][r]);
        float a   = (1.0f + ei) * (1.0f + eg);
        float num = c[cg][r] * a + (1.0f - eg) * (1.0f + ef);
        float den = (1.0f + ef) * a;
        float cn  = num * __builtin_amdgcn_rcpf(den);
        c[cg][r] = cn;
        float eo = __builtin_amdgcn_exp2f(-L1 * acc[3][r]);
        float ec = __builtin_amdgcn_exp2f(-L2 * cn);
        hr[r] = (1.0f - ec) * __builtin_amdgcn_rcpf((1.0f + eo) * (1.0f + ec));
      }

      // publish h (bf16); at w=15 this doubles as the output staging
      unsigned lo = ((unsigned)(unsigned short)f2bf(hr[0])) |
                    (((unsigned)(unsigned short)f2bf(hr[1])) << 16);
      unsigned hi = ((unsigned)(unsigned short)f2bf(hr[2])) |
                    (((unsigned)(unsigned short)f2bf(hr[3])) << 16);
      u32x2 v = {lo, hi};
      *(u32x2*)(&hbuf[w & 1][cg * 4096 + wrb]) = v;
    }
    __syncthreads();   // h published; at w=15 also all xg reads complete
  }

  // ---------------- epilogue: coalesced out from hbuf[1] ----------------
  // hbuf[1][chain][d] holds final h (bf16). 512 threads: chain = tid>>4,
  // d0 = (tid&15)*8 -> 16B swizzled read, 32B fp32 write per thread.
  {
    const int chain = tid >> 4;              // 0..31
    const int d0 = (tid & 15) * 8;
    const int byte = (chain * 256 + d0 * 2) ^ ((chain & 7) << 4);
    bf16x8 hv = *(const bf16x8*)(&hbuf[1][byte]);
    float* op = out + (long)(n0 + chain) * D_N + d0;
    f32x4 v0, v1;
#pragma unroll
    for (int e = 0; e < 4; ++e) {
      union { unsigned u; float f; } t0, t1;
      t0.u = ((unsigned)(unsigned short)hv[e]) << 16;
      t1.u = ((unsigned)(unsigned short)hv[4 + e]) << 16;
      v0[e] = t0.f; v1[e] = t1.f;
    }
    *(f32x4*)op = v0;
    *(f32x4*)(op + 4) = v1;
  }
}

// ---------------------------------------------------------------------------
extern "C" void kernel_launch(void* const* d_in, const int* in_sizes, int n_in,
                              void* d_out, int out_size, void* d_ws, size_t ws_size,
                              hipStream_t stream) {
  const float* x    = (const float*)d_in[0];
  const float* w_ih = (const float*)d_in[1];
  const float* w_hh = (const float*)d_in[2];
  const float* b_ih = (const float*)d_in[3];
  const float* b_hh = (const float*)d_in[4];
  float* out = (float*)d_out;

  fused_rnn<<<(B_N * S_N) / CH, 512, 0, stream>>>(x, w_ih, w_hh, b_ih, b_hh, out);
}

// Round 16
// 141.339 us; speedup vs baseline: 1.3982x; 1.3982x over previous
//
#include <hip/hip_runtime.h>

typedef __attribute__((ext_vector_type(8))) short bf16x8;
typedef __attribute__((ext_vector_type(4))) float f32x4;
typedef __attribute__((ext_vector_type(4))) _Float16 f16x4;
typedef __attribute__((ext_vector_type(2))) unsigned int u32x2;

#define B_N 8
#define S_N 2048
#define D_N 128
#define W_N 16
#define G_N 512
#define CH 64      /* chains per block */
#define ROWS 80    /* xg rows 0..78 used, 79 scratch */

#define L1 1.4426950408889634f   /* log2(e)   */
#define L2 2.8853900817779268f   /* 2*log2(e) */

// round-to-nearest-even fp32 -> bf16
__device__ __forceinline__ short f2bf(float f) {
  union { float f; unsigned u; } v; v.f = f;
  unsigned r = v.u + 0x7fffu + ((v.u >> 16) & 1u);
  return (short)(r >> 16);
}

__device__ __forceinline__ bf16x8 cvt8(const float* p) {
  f32x4 a = *(const f32x4*)p;
  f32x4 b = *(const f32x4*)(p + 4);
  bf16x8 v;
  v[0] = f2bf(a[0]); v[1] = f2bf(a[1]); v[2] = f2bf(a[2]); v[3] = f2bf(a[3]);
  v[4] = f2bf(b[0]); v[5] = f2bf(b[1]); v[6] = f2bf(b[2]); v[7] = f2bf(b[3]);
  return v;
}

// ---------------------------------------------------------------------------
// Fused LocalRNN, 64 chains/block, 256 blocks (1/CU, single round), 512 thr.
//
// OCCUPANCY VERDICT (R13/R14): unified VGPR+AGPR demand ~136+ pins this
// design at 2 waves/SIMD. (512,4)-style caps make hipcc split 64 arch +
// 64 AGPR and spill wf catastrophically (R3/R9/R14: 150-490 MB scratch).
// So: keep (512,2) (cap 256, no spill) and shorten the per-step critical
// path instead, using the ~140 regs of headroom:
//   1. xg PREFETCH: xg_s is read-only after phase 1 -> next step's 16 f16x4
//      gate-inits are ds_read during current step's MFMA/LSTM (32 regs),
//      removing xg LDS latency from the post-barrier path.
//   2. 7-trans LSTM (5 exp2 + 2 rcp, common-denominator; exact algebra):
//      cn = [c(1+ei)(1+eg) + (1-eg)(1+ef)] / [(1+ef)(1+ei)(1+eg)]
//      h  = (1-ec) / [(1+eo)(1+ec)]
// Wave wv owns gate tiles {wv,wv+8,wv+16,wv+24} -> i,f,g,o for one (chain,d)
// lane-local. 4 chain-groups/step. w_hh in VGPRs (time-shared with w_ih).
// h round-trips bf16 through double-buffered swizzled LDS; 1 barrier/step.
// Final h read back from hbuf[1] (no hfin registers).
// SPILL SENTINEL: WRITE_SIZE ~8.2 MB, VGPR_Count <= 256.
// ---------------------------------------------------------------------------
__global__ void __launch_bounds__(512, 2)
fused_rnn(const float* __restrict__ x, const float* __restrict__ w_ih,
          const float* __restrict__ w_hh, const float* __restrict__ b_ih,
          const float* __restrict__ b_hh, float* __restrict__ out) {
  __shared__ char xg_s[ROWS * 1024];        // 80 KB: f16 [row][gate], swizzled
  __shared__ char hbuf[2][CH * 256];        // 2x16 KB: bf16 [chain][k], swizzled

  const int tid  = threadIdx.x;
  const int lane = tid & 63;
  const int wv   = tid >> 6;                // 0..7, gate-slice
  const int lm   = lane & 15;
  const int q    = lane >> 4;
  const int n0   = blockIdx.x * CH;
  const int b    = n0 >> 11;                // 2048 chains per batch, CH | 2048
  const int s0   = n0 & (S_N - 1);

  // ---------------- phase 1: input projection into LDS (f16) ----------------
  bf16x8 wf[4][4];   // A fragments: weight[g = tg*16+lm][k = kt*32 + q*8 + j]
#pragma unroll
  for (int i = 0; i < 4; ++i) {
    const int g = (wv + 8 * i) * 16 + lm;
#pragma unroll
    for (int kt = 0; kt < 4; ++kt)
      wf[i][kt] = cvt8(w_ih + g * D_N + kt * 32 + q * 8);
  }

  {
    f32x4 bias[4];
#pragma unroll
    for (int i = 0; i < 4; ++i) {
      const int g0 = (wv + 8 * i) * 16 + 4 * q;
      f32x4 bi = *(const f32x4*)(b_ih + g0);
      f32x4 bh = *(const f32x4*)(b_hh + g0);
      bias[i].x = bi.x + bh.x; bias[i].y = bi.y + bh.y;
      bias[i].z = bi.z + bh.z; bias[i].w = bi.w + bh.w;
    }

#pragma unroll
    for (int rg = 0; rg < 5; ++rg) {
      const int r = rg * 16 + lm;            // xg row 0..79 (79 = scratch)
      const int t = s0 - (W_N - 1) + r;      // x timestep
      int tc = t < 0 ? 0 : t;
      tc = tc < S_N - 1 ? tc : S_N - 1;      // clamp (r=79 on last block)
      const bool valid = (t >= 0);
      const float* xr = x + ((long)b * S_N + tc) * D_N;
      bf16x8 xf[4];
#pragma unroll
      for (int kt = 0; kt < 4; ++kt) {
        if (valid) xf[kt] = cvt8(xr + kt * 32 + q * 8);
        else { bf16x8 z; for (int e = 0; e < 8; ++e) z[e] = 0; xf[kt] = z; }
      }
      f32x4 acc[4] = {{0,0,0,0},{0,0,0,0},{0,0,0,0},{0,0,0,0}};
#pragma unroll
      for (int i = 0; i < 4; ++i)
#pragma unroll
        for (int kt = 0; kt < 4; ++kt)
          acc[i] = __builtin_amdgcn_mfma_f32_16x16x32_bf16(wf[i][kt], xf[kt], acc[i], 0, 0, 0);
#pragma unroll
      for (int i = 0; i < 4; ++i) {
        const int g0 = (wv + 8 * i) * 16 + 4 * q;
        const int byte = (r * 1024 + g0 * 2) ^ ((r & 7) << 4);
        f16x4 hv;
        hv[0] = (_Float16)(acc[i][0] + bias[i].x);
        hv[1] = (_Float16)(acc[i][1] + bias[i].y);
        hv[2] = (_Float16)(acc[i][2] + bias[i].z);
        hv[3] = (_Float16)(acc[i][3] + bias[i].w);
        *(f16x4*)(xg_s + byte) = hv;
      }
    }
  }

  // reload fragment array with w_hh (time-shared registers)
#pragma unroll
  for (int i = 0; i < 4; ++i) {
    const int g = (wv + 8 * i) * 16 + lm;
#pragma unroll
    for (int kt = 0; kt < 4; ++kt)
      wf[i][kt] = cvt8(w_hh + g * D_N + kt * 32 + q * 8);
  }
  __syncthreads();

  // ---------------- phase 2: 16-step recurrence, 4 chain-groups ----------------
  const int swz = (lm & 7) << 4;
  const int wrb = (lm * 256 + (16 * wv + 4 * q) * 2) ^ swz;     // 8B h store
  int rdb[4];
#pragma unroll
  for (int kt = 0; kt < 4; ++kt)
    rdb[kt] = (lm * 256 + kt * 64 + q * 16) ^ swz;              // 16B h loads

  f32x4 c[4] = {{0,0,0,0},{0,0,0,0},{0,0,0,0},{0,0,0,0}};
  f16x4 xv[2][4][4];   // [step parity][cg][i] prefetched gate-inits (32 regs)

  // prologue: gate-inits for w = 0
#pragma unroll
  for (int cg = 0; cg < 4; ++cg) {
    const int row = cg * 16 + lm;
#pragma unroll
    for (int i = 0; i < 4; ++i) {
      const int g0 = (wv + 8 * i) * 16 + 4 * q;
      const int byte = (row * 1024 + g0 * 2) ^ ((row & 7) << 4);
      xv[0][cg][i] = *(const f16x4*)(xg_s + byte);
    }
  }

#pragma unroll
  for (int w = 0; w < W_N; ++w) {
    const int cur = w & 1, nxt = cur ^ 1;    // compile-time after unroll
#pragma unroll
    for (int cg = 0; cg < 4; ++cg) {
      // prefetch next step's gate-init early (latency hides under MFMA/LSTM)
      if (w < W_N - 1) {
        const int rown = cg * 16 + lm + w + 1;
#pragma unroll
        for (int i = 0; i < 4; ++i) {
          const int g0 = (wv + 8 * i) * 16 + 4 * q;
          const int byte = (rown * 1024 + g0 * 2) ^ ((rown & 7) << 4);
          xv[nxt][cg][i] = *(const f16x4*)(xg_s + byte);
        }
      }

      f32x4 acc[4];
#pragma unroll
      for (int i = 0; i < 4; ++i) {
        f16x4 t = xv[cur][cg][i];
        acc[i][0] = (float)t[0]; acc[i][1] = (float)t[1];
        acc[i][2] = (float)t[2]; acc[i][3] = (float)t[3];
      }

      if (w > 0) {
        const char* bb = hbuf[(w - 1) & 1] + cg * 4096;
        // K-split: 2 hf fragments live at a time
#pragma unroll
        for (int kh = 0; kh < 2; ++kh) {
          bf16x8 hf0 = *(const bf16x8*)(bb + rdb[2 * kh]);
          bf16x8 hf1 = *(const bf16x8*)(bb + rdb[2 * kh + 1]);
#pragma unroll
          for (int i = 0; i < 4; ++i) {
            acc[i] = __builtin_amdgcn_mfma_f32_16x16x32_bf16(wf[i][2 * kh],     hf0, acc[i], 0, 0, 0);
            acc[i] = __builtin_amdgcn_mfma_f32_16x16x32_bf16(wf[i][2 * kh + 1], hf1, acc[i], 0, 0, 0);
          }
        }
      }

      // acc[0]=i, acc[1]=f, acc[2]=g~, acc[3]=o for d=16wv+4q+r, chain=cg*16+lm
      float hr[4];
#pragma unroll
      for (int r = 0; r < 4; ++r) {
        float ei = __builtin_amdgcn_exp2f(-L1 * acc[0][r]);
        float ef = __builtin_amdgcn_exp2f(-L1 * acc[1][r]);
        float eg = __builtin_amdgcn_exp2f(-L2 * acc[2][r]);
        float a   = (1.0f + ei) * (1.0f + eg);
        float num = c[cg][r] * a + (1.0f - eg) * (1.0f + ef);
        float den = (1.0f + ef) * a;
        float cn  = num * __builtin_amdgcn_rcpf(den);
        c[cg][r] = cn;
        float eo = __builtin_amdgcn_exp2f(-L1 * acc[3][r]);
        float ec = __builtin_amdgcn_exp2f(-L2 * cn);
        hr[r] = (1.0f - ec) * __builtin_amdgcn_rcpf((1.0f + eo) * (1.0f + ec));
      }

      // publish h (bf16); at w=15 this doubles as the output staging
      unsigned lo = ((unsigned)(unsigned short)f2bf(hr[0])) |
                    (((unsigned)(unsigned short)f2bf(hr[1])) << 16);
      unsigned hi = ((unsigned)(unsigned short)f2bf(hr[2])) |
                    (((unsigned)(unsigned short)f2bf(hr[3])) << 16);
      u32x2 v = {lo, hi};
      *(u32x2*)(&hbuf[cur][cg * 4096 + wrb]) = v;
    }
    __syncthreads();   // h published; xg prefetch reads also drain here
  }

  // ---------------- epilogue: coalesced out from hbuf[1] ----------------
  // hbuf[1] holds final h (w=15 wrote parity 1). chain 0..63, d 0..127.
#pragma unroll
  for (int p = 0; p < 2; ++p) {
    const int idx = p * 512 + tid;           // 0..1023
    const int chain = idx >> 4;              // 0..63
    const int d0 = (idx & 15) * 8;
    const int byte = (chain * 256 + d0 * 2) ^ ((chain & 7) << 4);
    bf16x8 hv = *(const bf16x8*)(&hbuf[1][byte]);
    float* op = out + (long)(n0 + chain) * D_N + d0;
    f32x4 v0, v1;
#pragma unroll
    for (int e = 0; e < 4; ++e) {
      union { unsigned u; float f; } t0, t1;
      t0.u = ((unsigned)(unsigned short)hv[e]) << 16;
      t1.u = ((unsigned)(unsigned short)hv[4 + e]) << 16;
      v0[e] = t0.f; v1[e] = t1.f;
    }
    *(f32x4*)op = v0;
    *(f32x4*)(op + 4) = v1;
  }
}

// ---------------------------------------------------------------------------
extern "C" void kernel_launch(void* const* d_in, const int* in_sizes, int n_in,
                              void* d_out, int out_size, void* d_ws, size_t ws_size,
                              hipStream_t stream) {
  const float* x    = (const float*)d_in[0];
  const float* w_ih = (const float*)d_in[1];
  const float* w_hh = (const float*)d_in[2];
  const float* b_ih = (const float*)d_in[3];
  const float* b_hh = (const float*)d_in[4];
  float* out = (float*)d_out;

  fused_rnn<<<(B_N * S_N) / CH, 512, 0, stream>>>(x, w_ih, w_hh, b_ih, b_hh, out);
}